// Round 2
// baseline (476.985 us; speedup 1.0000x reference)
//
#include <hip/hip_runtime.h>
#include <hip/hip_bf16.h>
#include <math.h>

#define NTOK 2048
#define HDIM 1024
#define NEXP 8
#define FDIM 3584
#define NHEADS 16
#define NLOW 204
#define NHIGH 204
#define BK 32
#define LDST 40   // padded LDS row stride in bf16 elems (80 B, 16B-aligned, spreads banks)

typedef __bf16 bf16x8 __attribute__((ext_vector_type(8)));
typedef float f32x4 __attribute__((ext_vector_type(4)));

// ---------------- K1: router logits + softmax top2 + L1 norm ----------------
__global__ __launch_bounds__(256) void k_router(
    const float* __restrict__ x, const float* __restrict__ gw,
    float* __restrict__ logits, float* __restrict__ l1,
    int* __restrict__ sel0, int* __restrict__ sel1,
    float* __restrict__ rw0, float* __restrict__ rw1)
{
    __shared__ float sgw[NEXP * HDIM];
    int tid = threadIdx.x;
    for (int i = tid; i < NEXP * HDIM; i += 256) sgw[i] = gw[i];
    __syncthreads();
    int wv = tid >> 6, lane = tid & 63;
    int t = blockIdx.x * 4 + wv;
    const float* xr = x + (size_t)t * HDIM;
    float acc[NEXP];
#pragma unroll
    for (int e = 0; e < NEXP; ++e) acc[e] = 0.f;
    float al1 = 0.f;
    for (int h = lane; h < HDIM; h += 64) {
        float xv = xr[h];
        al1 += fabsf(xv);
#pragma unroll
        for (int e = 0; e < NEXP; ++e) acc[e] += xv * sgw[e * HDIM + h];
    }
#pragma unroll
    for (int off = 32; off > 0; off >>= 1) {
#pragma unroll
        for (int e = 0; e < NEXP; ++e) acc[e] += __shfl_xor(acc[e], off);
        al1 += __shfl_xor(al1, off);
    }
    if (lane < NEXP) logits[t * NEXP + lane] = acc[lane];
    if (lane == 0) {
        l1[t] = al1;
        float m = acc[0];
#pragma unroll
        for (int e = 1; e < NEXP; ++e) m = fmaxf(m, acc[e]);
        float p[NEXP], s = 0.f;
#pragma unroll
        for (int e = 0; e < NEXP; ++e) { p[e] = expf(acc[e] - m); s += p[e]; }
        float inv = 1.f / s;
        float b0 = -1.f, b1 = -1.f; int i0 = 0, i1 = 0;
#pragma unroll
        for (int e = 0; e < NEXP; ++e) {
            float r = p[e] * inv;
            if (r > b0) { b1 = b0; i1 = i0; b0 = r; i0 = e; }
            else if (r > b1) { b1 = r; i1 = e; }
        }
        sel0[t] = i0; sel1[t] = i1; rw0[t] = b0; rw1[t] = b1;
    }
}

// ---------------- K2: attention-based token scores ----------------
__global__ __launch_bounds__(256) void k_attn(
    const float* __restrict__ attn, const float* __restrict__ l1,
    float* __restrict__ scores)
{
    int i = blockIdx.x, tid = threadIdx.x;
    float acc = 0.f;
    for (int h = 0; h < NHEADS; ++h) {
        const float4* p = (const float4*)(attn + ((size_t)h * NTOK + i) * NTOK);
        for (int j = tid; j < NTOK / 4; j += 256) {
            float4 v = p[j];
            acc += v.x + v.y + v.z + v.w;
        }
    }
    __shared__ float red[256];
    red[tid] = acc; __syncthreads();
    for (int s = 128; s > 0; s >>= 1) {
        if (tid < s) red[tid] += red[tid + s];
        __syncthreads();
    }
    if (tid == 0) scores[i] = red[0] / (16.f * (float)(NTOK - i)) * l1[i];
}

// ---------------- K3: exact stable-rank top-k masks + final routing weights --
__global__ __launch_bounds__(256) void k_rank(
    const float* __restrict__ scores, const float* __restrict__ rw0,
    const float* __restrict__ rw1, float* __restrict__ w0f, float* __restrict__ w1f)
{
    __shared__ float s[NTOK];
    int tid = threadIdx.x;
    for (int i = tid; i < NTOK; i += 256) s[i] = scores[i];
    __syncthreads();
    int t = blockIdx.x * 256 + tid;
    float st = s[t];
    int cl = 0, ch = 0;
    for (int j = 0; j < NTOK; ++j) {
        float sj = s[j];
        int tie = (sj == st) && (j < t);
        cl += (sj < st) || tie;
        ch += (sj > st) || tie;
    }
    bool in_low = cl < NLOW, keep = ch < NHIGH;
    float a = rw0[t], b = rw1[t];
    float n0 = 1.f, n1 = (b < 0.5f * a) ? 0.f : 1.f;
    if (in_low) { n0 = 0.f; n1 = 0.f; }
    if (keep)   { n0 = 1.f; n1 = 1.f; }
    a *= n0; b *= n1;
    float d = a + b;
    if (d > 0.f) { a /= d; b /= d; }
    w0f[t] = a; w1f[t] = b;
}

// ---------------- K4: per-expert token list build (deterministic) ----------
__global__ __launch_bounds__(512) void k_build(
    const int* __restrict__ sel0, const int* __restrict__ sel1,
    const float* __restrict__ w0f, const float* __restrict__ w1f,
    int* __restrict__ tok, float* __restrict__ wgt,
    int* __restrict__ counts, int* __restrict__ offs)
{
    int tid = threadIdx.x;
    int e = tid >> 6, lane = tid & 63;
    unsigned long long below = (1ull << lane) - 1ull;
    int base = 0;
    for (int r = 0; r < NTOK / 64; ++r) {
        int t = r * 64 + lane;
        bool f0 = (sel0[t] == e) && (w0f[t] > 0.f);
        unsigned long long m0 = __ballot(f0);
        if (f0) {
            int pos = base + __popcll(m0 & below);
            tok[e * NTOK + pos] = t; wgt[e * NTOK + pos] = w0f[t];
        }
        base += __popcll(m0);
        bool f1 = (sel1[t] == e) && (w1f[t] > 0.f);
        unsigned long long m1 = __ballot(f1);
        if (f1) {
            int pos = base + __popcll(m1 & below);
            tok[e * NTOK + pos] = t; wgt[e * NTOK + pos] = w1f[t];
        }
        base += __popcll(m1);
    }
    if (lane == 0) counts[e] = base;
    __syncthreads();
    if (tid == 0) {
        int o = 0;
        for (int i = 0; i < NEXP; ++i) { offs[i] = o; o += counts[i]; }
    }
}

// ---------------- K5: zero the MoE output region ----------------
__global__ __launch_bounds__(256) void k_zero(float4* __restrict__ out)
{
    out[blockIdx.x * 256 + threadIdx.x] = make_float4(0.f, 0.f, 0.f, 0.f);
}

__device__ inline void stage8(__hip_bfloat16* dst, const float* src)
{
    float4 a = *(const float4*)src;
    float4 b = *(const float4*)(src + 4);
    bf16x8 v;
    v[0] = (__bf16)a.x; v[1] = (__bf16)a.y; v[2] = (__bf16)a.z; v[3] = (__bf16)a.w;
    v[4] = (__bf16)b.x; v[5] = (__bf16)b.y; v[6] = (__bf16)b.z; v[7] = (__bf16)b.w;
    *(bf16x8*)dst = v;
}

// ---------------- K6: phase-1 grouped GEMM: act = silu(x@w1^T)*(x@w3^T)*cw --
__global__ __launch_bounds__(256) void k_ffn1(
    const float* __restrict__ x, const float* __restrict__ w1,
    const float* __restrict__ w3,
    const int* __restrict__ tok, const float* __restrict__ wgt,
    const int* __restrict__ counts, const int* __restrict__ offs,
    __hip_bfloat16* __restrict__ act)
{
    int e = blockIdx.z;
    int cnt = counts[e];
    int m0 = blockIdx.y * 64;
    if (m0 >= cnt) return;
    int f0 = blockIdx.x * 64;
    int tid = threadIdx.x;
    __shared__ __hip_bfloat16 sX[64 * LDST], sW1[64 * LDST], sW3[64 * LDST];
    __shared__ int sTok[64];
    __shared__ float sWgt[64];
    if (tid < 64) {
        int row = m0 + tid;
        int rr = (row < cnt) ? row : (cnt - 1);
        sTok[tid] = tok[e * NTOK + rr];
        sWgt[tid] = (row < cnt) ? wgt[e * NTOK + row] : 0.f;
    }
    __syncthreads();

    int r = tid >> 2, kk = (tid & 3) * 8;
    const float* xp  = x  + (size_t)sTok[r] * HDIM + kk;
    const float* w1p = w1 + ((size_t)e * FDIM + f0 + r) * HDIM + kk;
    const float* w3p = w3 + ((size_t)e * FDIM + f0 + r) * HDIM + kk;

    int wv = tid >> 6, lane = tid & 63;
    f32x4 acc1[4] = {}, acc3[4] = {};
    const int rowA = wv * 16 + (lane & 15);
    const int kfrag = (lane >> 4) * 8;

    for (int k0 = 0; k0 < HDIM; k0 += BK) {
        stage8(&sX[r * LDST + kk], xp + k0);
        stage8(&sW1[r * LDST + kk], w1p + k0);
        stage8(&sW3[r * LDST + kk], w3p + k0);
        __syncthreads();
        bf16x8 a = *(const bf16x8*)&sX[rowA * LDST + kfrag];
#pragma unroll
        for (int c = 0; c < 4; ++c) {
            bf16x8 b1 = *(const bf16x8*)&sW1[(c * 16 + (lane & 15)) * LDST + kfrag];
            acc1[c] = __builtin_amdgcn_mfma_f32_16x16x32_bf16(a, b1, acc1[c], 0, 0, 0);
            bf16x8 b3 = *(const bf16x8*)&sW3[(c * 16 + (lane & 15)) * LDST + kfrag];
            acc3[c] = __builtin_amdgcn_mfma_f32_16x16x32_bf16(a, b3, acc3[c], 0, 0, 0);
        }
        __syncthreads();
    }
    int soff = offs[e];
#pragma unroll
    for (int c = 0; c < 4; ++c) {
#pragma unroll
        for (int rr = 0; rr < 4; ++rr) {
            int rloc = wv * 16 + (lane >> 4) * 4 + rr;
            if (m0 + rloc < cnt) {
                float hv = acc1[c][rr], gv = acc3[c][rr];
                float av = hv / (1.f + expf(-hv)) * gv * sWgt[rloc];
                act[(size_t)(soff + m0 + rloc) * FDIM + f0 + c * 16 + (lane & 15)] =
                    (__hip_bfloat16)av;
            }
        }
    }
}

// ---------------- K7: phase-2 grouped GEMM: out += act @ w2^T ----------------
__global__ __launch_bounds__(256) void k_ffn2(
    const __hip_bfloat16* __restrict__ act, const float* __restrict__ w2,
    const int* __restrict__ tok, const int* __restrict__ counts,
    const int* __restrict__ offs, float* __restrict__ out)
{
    int e = blockIdx.z;
    int cnt = counts[e];
    int m0 = blockIdx.y * 64;
    if (m0 >= cnt) return;
    int h0 = blockIdx.x * 64;
    int tid = threadIdx.x;
    __shared__ __hip_bfloat16 sA[64 * LDST], sB[64 * LDST];
    __shared__ int sTok[64];
    if (tid < 64) {
        int row = m0 + tid;
        sTok[tid] = (row < cnt) ? tok[e * NTOK + row] : 0;
    }
    __syncthreads();
    int soff = offs[e];
    int r = tid >> 2, kk = (tid & 3) * 8;
    int arow = (m0 + r < cnt) ? (m0 + r) : (cnt - 1);
    const __hip_bfloat16* ap = act + (size_t)(soff + arow) * FDIM + kk;
    const float* bp = w2 + ((size_t)e * HDIM + h0 + r) * FDIM + kk;
    int wv = tid >> 6, lane = tid & 63;
    f32x4 acc[4] = {};
    const int rowA = wv * 16 + (lane & 15);
    const int kfrag = (lane >> 4) * 8;
    for (int k0 = 0; k0 < FDIM; k0 += BK) {
        *(bf16x8*)&sA[r * LDST + kk] = *(const bf16x8*)(ap + k0);
        stage8(&sB[r * LDST + kk], bp + k0);
        __syncthreads();
        bf16x8 a = *(const bf16x8*)&sA[rowA * LDST + kfrag];
#pragma unroll
        for (int c = 0; c < 4; ++c) {
            bf16x8 b = *(const bf16x8*)&sB[(c * 16 + (lane & 15)) * LDST + kfrag];
            acc[c] = __builtin_amdgcn_mfma_f32_16x16x32_bf16(a, b, acc[c], 0, 0, 0);
        }
        __syncthreads();
    }
#pragma unroll
    for (int c = 0; c < 4; ++c) {
#pragma unroll
        for (int rr2 = 0; rr2 < 4; ++rr2) {
            int rloc = wv * 16 + (lane >> 4) * 4 + rr2;
            if (m0 + rloc < cnt) {
                int t = sTok[rloc];
                atomicAdd(&out[(size_t)t * HDIM + h0 + c * 16 + (lane & 15)], acc[c][rr2]);
            }
        }
    }
}

extern "C" void kernel_launch(void* const* d_in, const int* in_sizes, int n_in,
                              void* d_out, int out_size, void* d_ws, size_t ws_size,
                              hipStream_t stream)
{
    const float* x    = (const float*)d_in[0];
    const float* attn = (const float*)d_in[1];
    const float* gw   = (const float*)d_in[2];
    const float* w1   = (const float*)d_in[3];
    const float* w2   = (const float*)d_in[4];
    const float* w3   = (const float*)d_in[5];
    float* out = (float*)d_out;
    float* logits = out + (size_t)NTOK * HDIM;

    char* ws = (char*)d_ws;
    float* l1     = (float*)(ws + 0);
    float* scores = (float*)(ws + 8192);
    int*   sel0   = (int*)(ws + 16384);
    int*   sel1   = (int*)(ws + 24576);
    float* rw0    = (float*)(ws + 32768);
    float* rw1    = (float*)(ws + 40960);
    float* w0f    = (float*)(ws + 49152);
    float* w1f    = (float*)(ws + 57344);
    int*   counts = (int*)(ws + 65536);
    int*   offs   = (int*)(ws + 65600);
    int*   tok    = (int*)(ws + 73728);
    float* wgt    = (float*)(ws + 143360);
    __hip_bfloat16* act = (__hip_bfloat16*)(ws + 1048576);

    k_router<<<NTOK / 4, 256, 0, stream>>>(x, gw, logits, l1, sel0, sel1, rw0, rw1);
    k_attn<<<NTOK, 256, 0, stream>>>(attn, l1, scores);
    k_rank<<<NEXP, 256, 0, stream>>>(scores, rw0, rw1, w0f, w1f);
    k_build<<<1, 512, 0, stream>>>(sel0, sel1, w0f, w1f, tok, wgt, counts, offs);
    k_zero<<<NTOK, 256, 0, stream>>>((float4*)out);
    k_ffn1<<<dim3(FDIM / 64, NTOK / 64, NEXP), 256, 0, stream>>>(
        x, w1, w3, tok, wgt, counts, offs, act);
    k_ffn2<<<dim3(HDIM / 64, NTOK / 64, NEXP), 256, 0, stream>>>(
        act, w2, tok, counts, offs, out);
}